// Round 1
// 207.252 us; speedup vs baseline: 1.0083x; 1.0083x over previous
//
#include <hip/hip_runtime.h>

#define BB 32
#define TT 36
#define NN 10000
#define FF 3
#define HH 10
#define RR 20
#define NQ (NN / 4)              // 2500 node-quads per batch
#define NC (NN * FF / 4)         // 7500 float4 columns per (b,t) row
#define NPB ((NC + 255) / 256)   // 30 stage-1 blocks along columns
#define PB ((NQ + 255) / 256)    // 10 pred chunks per batch

// ws layout (floats):
//   [0, BB*NN)            : time_mean (NaN where node all-NaN)
//   [+BB*NPB*RR]          : per-(b,block,region) partial sum of node means
//   [+BB*NPB*RR]          : per-(b,block,region) partial count of valid nodes
// No memset needed: every stage-1 block fully writes its own partial slice.

// Stage 1, column-owner form: thread owns ONE float4 column c across all T.
// ch0 words (multiples of 3) within column c: c=3k -> {.x=node 4k, .w=node 4k+1},
// c=3k+1 -> {.z=node 4k+2}, c=3k+2 -> {.y=node 4k+3}.
// One 16B load + ~6 VALU per iteration, no barriers in the loop.
__global__ __launch_bounds__(256) void k_time_mean(
        const float4* __restrict__ seq4,
        const int* __restrict__ cid,
        float* __restrict__ tm,
        float* __restrict__ psum,
        float* __restrict__ pcnt) {
    __shared__ float ls[RR];
    __shared__ float lc[RR];
    const int b = blockIdx.y;
    const int c = blockIdx.x * blockDim.x + threadIdx.x;   // column 0..7499
    if (threadIdx.x < RR) { ls[threadIdx.x] = 0.f; lc[threadIdx.x] = 0.f; }
    __syncthreads();

    if (c < NC) {
        const int k = c / 3;
        const int r = c - 3 * k;            // 0,1,2 — lane class
        const float4* p = seq4 + (size_t)b * TT * NC + c;

        float sA = 0.f, sB = 0.f;
        int   cA = 0,   cB = 0;
        #pragma unroll
        for (int t = 0; t < TT; ++t) {
            const float4 a = p[(size_t)t * NC];
            // predicated component select: no branches, no divergence
            const float vA = (r == 0) ? a.x : ((r == 1) ? a.z : a.y);
            const float vB = a.w;           // meaningful only for r==0
            if (vA == vA)           { sA += vA; cA++; }
            if (r == 0 && vB == vB) { sB += vB; cB++; }
        }

        const float nanf_ = __int_as_float(0x7fc00000);
        const int nA = (r == 0) ? 4 * k : ((r == 1) ? 4 * k + 2 : 4 * k + 3);
        const float mA = cA ? sA / (float)cA : nanf_;
        tm[b * NN + nA] = mA;
        if (cA) {
            const int rg = cid[nA];
            atomicAdd(&ls[rg], mA);
            atomicAdd(&lc[rg], 1.f);
        }
        if (r == 0) {
            const int nB = 4 * k + 1;
            const float mB = cB ? sB / (float)cB : nanf_;
            tm[b * NN + nB] = mB;
            if (cB) {
                const int rg = cid[nB];
                atomicAdd(&ls[rg], mB);
                atomicAdd(&lc[rg], 1.f);
            }
        }
    }

    __syncthreads();
    // deterministic per-block partials — no init, no global atomics
    if (threadIdx.x < RR) {
        const int o = (b * NPB + blockIdx.x) * RR + threadIdx.x;
        psum[o] = ls[threadIdx.x];
        pcnt[o] = lc[threadIdx.x];
    }
}

// Fused stage 2: blocks [0, BB*PB) do the pred tile-copy (with a cold NaN
// backfill path that self-computes g1 from the partials); block BB*PB does
// the regional means + g2 backfill. Regional runs concurrently with pred.
__global__ __launch_bounds__(256) void k_fused(
        const float* __restrict__ tm,
        const float* __restrict__ psum,
        const float* __restrict__ pcnt,
        float* __restrict__ out) {
    const int tid = threadIdx.x;
    const int gb = blockIdx.x;
    __shared__ float shs[4], shc[4];

    if (gb < BB * PB) {
        // ---- pred path ----
        const int b = gb / PB;
        const int q = (gb - b * PB) * 256 + tid;      // quad 0..2499
        float4 v = {0.f, 0.f, 0.f, 0.f};
        int bad = 0;
        if (q < NQ) {
            v = ((const float4*)tm)[(size_t)b * NQ + q];
            bad = (!(v.x == v.x)) | (!(v.y == v.y)) |
                  (!(v.z == v.z)) | (!(v.w == v.w));
        }
        // cold path: some node was all-NaN (essentially never at 5% NaN, T=36)
        if (__syncthreads_or(bad)) {
            float s = 0.f, cc = 0.f;
            for (int i = tid; i < BB * NPB * RR; i += 256) {
                s += psum[i]; cc += pcnt[i];
            }
            for (int off = 32; off > 0; off >>= 1) {
                s  += __shfl_down(s,  off, 64);
                cc += __shfl_down(cc, off, 64);
            }
            if ((tid & 63) == 0) { shs[tid >> 6] = s; shc[tid >> 6] = cc; }
            __syncthreads();
            const float g1 = (shs[0] + shs[1] + shs[2] + shs[3]) /
                             (shc[0] + shc[1] + shc[2] + shc[3]);
            if (!(v.x == v.x)) v.x = g1;
            if (!(v.y == v.y)) v.y = g1;
            if (!(v.z == v.z)) v.z = g1;
            if (!(v.w == v.w)) v.w = g1;
        }
        if (q < NQ) {
            float4* o = (float4*)out + (size_t)b * HH * NQ + q;
            #pragma unroll
            for (int h = 0; h < HH; ++h)
                o[(size_t)h * NQ] = v;
        }
    } else {
        // ---- regional path: 640 (b,region) items over 256 threads ----
        float val[3]; int vd[3];
        float sv = 0.f, sc = 0.f;
        #pragma unroll
        for (int j = 0; j < 3; ++j) {
            val[j] = 0.f; vd[j] = 0;
            const int i = tid + j * 256;
            if (i < BB * RR) {
                const int b = i / RR, r = i - b * RR;
                float s = 0.f, c = 0.f;
                #pragma unroll
                for (int x = 0; x < NPB; ++x) {
                    const int o = (b * NPB + x) * RR + r;
                    s += psum[o];
                    c += pcnt[o];
                }
                if (c > 0.f) { val[j] = s / c; vd[j] = 1; sv += val[j]; sc += 1.f; }
            }
        }
        for (int off = 32; off > 0; off >>= 1) {
            sv += __shfl_down(sv, off, 64);
            sc += __shfl_down(sc, off, 64);
        }
        if ((tid & 63) == 0) { shs[tid >> 6] = sv; shc[tid >> 6] = sc; }
        __syncthreads();
        const float g2 = (shs[0] + shs[1] + shs[2] + shs[3]) /
                         (shc[0] + shc[1] + shc[2] + shc[3]);
        float* out_reg = out + (size_t)BB * HH * NN;
        #pragma unroll
        for (int j = 0; j < 3; ++j) {
            const int i = tid + j * 256;
            if (i < BB * RR) {
                const int b = i / RR, r = i - b * RR;
                const float o = vd[j] ? val[j] : g2;
                #pragma unroll
                for (int h = 0; h < HH; ++h)
                    out_reg[(size_t)(b * HH + h) * RR + r] = o;
            }
        }
    }
}

extern "C" void kernel_launch(void* const* d_in, const int* in_sizes, int n_in,
                              void* d_out, int out_size, void* d_ws, size_t ws_size,
                              hipStream_t stream) {
    const float* seq = (const float*)d_in[0];
    const int*   cid = (const int*)d_in[1];
    float* out = (float*)d_out;

    float* ws   = (float*)d_ws;
    float* tm   = ws;                       // BB*NN
    float* psum = tm + BB * NN;             // BB*NPB*RR
    float* pcnt = psum + BB * NPB * RR;     // BB*NPB*RR

    dim3 blk(256);
    dim3 grdA(NPB, BB);                     // 30 x 32 = 960 blocks
    k_time_mean<<<grdA, blk, 0, stream>>>((const float4*)seq, cid, tm, psum, pcnt);
    k_fused<<<dim3(BB * PB + 1), blk, 0, stream>>>(tm, psum, pcnt, out);
}